// Round 1
// baseline (830.268 us; speedup 1.0000x reference)
//
#include <hip/hip_runtime.h>
#include <hip/hip_bf16.h>
#include <math.h>

#define N_NODES 50000
#define N_EDGES 800000
#define NFEAT 3
#define C1 512
#define C2 256
#define C3 128
#define NGRAPH 100
#define NCLS 2

// ---------------- degree / normalization ----------------

__global__ void count_edges(const int* __restrict__ col, int* __restrict__ counts) {
    int e = blockIdx.x * blockDim.x + threadIdx.x;
    if (e < N_EDGES) atomicAdd(&counts[col[e]], 1);
}

__global__ void compute_dis(const int* __restrict__ counts, float* __restrict__ dis) {
    int i = blockIdx.x * blockDim.x + threadIdx.x;
    if (i < N_NODES) dis[i] = rsqrtf((float)(counts[i] + 1)); // +1 self loop; deg>=1 always
}

// ---------------- CSR build: 2-level scan + scatter ----------------

__global__ void scan_chunks(const int* __restrict__ counts, int* __restrict__ offsets,
                            int* __restrict__ chunksums) {
    __shared__ int s[256];
    int b = blockIdx.x, t = threadIdx.x;
    int i = b * 256 + t;
    int v = (i < N_NODES) ? counts[i] : 0;
    s[t] = v;
    __syncthreads();
    for (int d = 1; d < 256; d <<= 1) {
        int add = (t >= d) ? s[t - d] : 0;
        __syncthreads();
        s[t] += add;
        __syncthreads();
    }
    if (i < N_NODES) offsets[i + 1] = s[t];
    if (t == 255) chunksums[b] = s[255];
}

__global__ void scan_sums(int* __restrict__ chunksums, int nchunks) {
    __shared__ int s[256];
    int t = threadIdx.x;
    int v = (t < nchunks) ? chunksums[t] : 0;
    s[t] = v;
    __syncthreads();
    for (int d = 1; d < 256; d <<= 1) {
        int add = (t >= d) ? s[t - d] : 0;
        __syncthreads();
        s[t] += add;
        __syncthreads();
    }
    if (t < nchunks) chunksums[t] = (t == 0) ? 0 : s[t - 1]; // exclusive chunk offsets
}

__global__ void finalize_offsets(int* __restrict__ offsets, const int* __restrict__ chunkoffs) {
    int i = blockIdx.x * blockDim.x + threadIdx.x;
    if (i < N_NODES) offsets[i + 1] += chunkoffs[i / 256];
    if (i == 0) offsets[0] = 0;
}

__global__ void init_cursor(const int* __restrict__ offsets, int* __restrict__ cursor) {
    int i = blockIdx.x * blockDim.x + threadIdx.x;
    if (i < N_NODES) cursor[i] = offsets[i];
}

__global__ void scatter_edges(const int* __restrict__ rowi, const int* __restrict__ coli,
                              const float* __restrict__ dis, int* __restrict__ cursor,
                              int* __restrict__ csr_src, float* __restrict__ csr_w) {
    int e = blockIdx.x * blockDim.x + threadIdx.x;
    if (e < N_EDGES) {
        int r = rowi[e], c = coli[e];
        int p = atomicAdd(&cursor[c], 1);
        csr_src[p] = r;
        csr_w[p] = dis[r] * dis[c];
    }
}

// ---------------- layer 1: aggregate 3 feats, then tiny GEMM ----------------

__global__ void agg_feat3(const float* __restrict__ x, const int* __restrict__ offsets,
                          const int* __restrict__ csr_src, const float* __restrict__ csr_w,
                          const float* __restrict__ dis, float* __restrict__ aggx) {
    int i = blockIdx.x * blockDim.x + threadIdx.x;
    if (i >= N_NODES) return;
    float d = dis[i];
    float ws = d * d;
    float a0 = ws * x[i * 3 + 0], a1 = ws * x[i * 3 + 1], a2 = ws * x[i * 3 + 2];
    int s = offsets[i], e = offsets[i + 1];
    for (int p = s; p < e; ++p) {
        int r = csr_src[p];
        float w = csr_w[p];
        a0 += w * x[r * 3 + 0];
        a1 += w * x[r * 3 + 1];
        a2 += w * x[r * 3 + 2];
    }
    aggx[i * 3 + 0] = a0; aggx[i * 3 + 1] = a1; aggx[i * 3 + 2] = a2;
}

__global__ void layer1(const float* __restrict__ aggx, const float* __restrict__ W1,
                       const float* __restrict__ b1, float* __restrict__ h1) {
    int i = blockIdx.x;
    int t = threadIdx.x;
    float a0 = aggx[i * 3 + 0], a1 = aggx[i * 3 + 1], a2 = aggx[i * 3 + 2];
#pragma unroll
    for (int jj = 0; jj < 2; ++jj) {
        int j = t + jj * 256;
        float v = a0 * W1[j] + a1 * W1[C1 + j] + a2 * W1[2 * C1 + j] + b1[j];
        h1[(size_t)i * C1 + j] = fmaxf(v, 0.f);
    }
}

// ---------------- fp32 tiled GEMM: C[M x Nn] = A[M x K] * B[K x Nn] ----------------

template <int K>
__global__ void gemm_nn(const float* __restrict__ A, const float* __restrict__ B,
                        float* __restrict__ Cmat, int M, int Nn) {
    __shared__ float As[16][64];
    __shared__ float Bs[16][64];
    int bm = blockIdx.x * 64;
    int bn = blockIdx.y * 64;
    int t = threadIdx.x;
    int tm = (t / 16) * 4;
    int tn = (t % 16) * 4;
    int la_row = t / 4;
    int la_k = (t % 4) * 4;
    int lb_k = t / 16;
    int lb_col = (t % 16) * 4;
    float acc[4][4] = {};
    for (int k0 = 0; k0 < K; k0 += 16) {
        int ar = bm + la_row;
        float4 av = make_float4(0.f, 0.f, 0.f, 0.f);
        if (ar < M) av = *(const float4*)&A[(size_t)ar * K + k0 + la_k];
        As[la_k + 0][la_row] = av.x;
        As[la_k + 1][la_row] = av.y;
        As[la_k + 2][la_row] = av.z;
        As[la_k + 3][la_row] = av.w;
        float4 bv = *(const float4*)&B[(size_t)(k0 + lb_k) * Nn + bn + lb_col];
        *(float4*)&Bs[lb_k][lb_col] = bv;
        __syncthreads();
#pragma unroll
        for (int k = 0; k < 16; ++k) {
            float av4[4], bv4[4];
#pragma unroll
            for (int q = 0; q < 4; ++q) av4[q] = As[k][tm + q];
#pragma unroll
            for (int q = 0; q < 4; ++q) bv4[q] = Bs[k][tn + q];
#pragma unroll
            for (int mi = 0; mi < 4; ++mi)
#pragma unroll
                for (int ni = 0; ni < 4; ++ni) acc[mi][ni] += av4[mi] * bv4[ni];
        }
        __syncthreads();
    }
#pragma unroll
    for (int mi = 0; mi < 4; ++mi) {
        int r = bm + tm + mi;
        if (r < M) {
            float4 v = make_float4(acc[mi][0], acc[mi][1], acc[mi][2], acc[mi][3]);
            *(float4*)&Cmat[(size_t)r * Nn + bn + tn] = v;
        }
    }
}

// ---------------- aggregation over CSR, fused bias + relu ----------------

template <int C>
__global__ void aggregate(const float* __restrict__ m, const int* __restrict__ offsets,
                          const int* __restrict__ csr_src, const float* __restrict__ csr_w,
                          const float* __restrict__ dis, const float* __restrict__ bias,
                          float* __restrict__ out) {
    int i = blockIdx.x;
    int t = threadIdx.x;
    float d = dis[i];
    float acc = d * d * m[(size_t)i * C + t];
    int s = offsets[i], e = offsets[i + 1];
    for (int p = s; p < e; ++p) {
        int r = csr_src[p];
        float w = csr_w[p];
        acc += w * m[(size_t)r * C + t];
    }
    acc += bias[t];
    out[(size_t)i * C + t] = fmaxf(acc, 0.f);
}

// ---------------- mean pool per graph + linear head + log_softmax ----------------

__global__ void pool_head(const float* __restrict__ h3, const int* __restrict__ batch,
                          const float* __restrict__ Wc, const float* __restrict__ bc,
                          float* __restrict__ outp) {
    int g = blockIdx.x;
    int t = threadIdx.x; // 128 threads = C3
    int lo = 0, hi = N_NODES;
    while (lo < hi) { int mid = (lo + hi) >> 1; if (batch[mid] < g) lo = mid + 1; else hi = mid; }
    int start = lo;
    hi = N_NODES;
    while (lo < hi) { int mid = (lo + hi) >> 1; if (batch[mid] < g + 1) lo = mid + 1; else hi = mid; }
    int end = lo;
    float sum = 0.f;
    for (int i = start; i < end; ++i) sum += h3[(size_t)i * C3 + t];
    float cnt = (float)(end - start);
    float pooled = sum / fmaxf(cnt, 1.f);
    float p0 = pooled * Wc[t * 2 + 0];
    float p1 = pooled * Wc[t * 2 + 1];
#pragma unroll
    for (int o = 32; o > 0; o >>= 1) {
        p0 += __shfl_down(p0, o);
        p1 += __shfl_down(p1, o);
    }
    __shared__ float r0[2], r1[2];
    int wid = t >> 6, lane = t & 63;
    if (lane == 0) { r0[wid] = p0; r1[wid] = p1; }
    __syncthreads();
    if (t == 0) {
        float l0 = r0[0] + r0[1] + bc[0];
        float l1 = r1[0] + r1[1] + bc[1];
        float mx = fmaxf(l0, l1);
        float lse = mx + logf(expf(l0 - mx) + expf(l1 - mx));
        outp[g * 2 + 0] = l0 - lse;
        outp[g * 2 + 1] = l1 - lse;
    }
}

// ---------------- launch ----------------

extern "C" void kernel_launch(void* const* d_in, const int* in_sizes, int n_in,
                              void* d_out, int out_size, void* d_ws, size_t ws_size,
                              hipStream_t stream) {
    const float* x = (const float*)d_in[0];
    const float* W1 = (const float*)d_in[1];
    const float* b1 = (const float*)d_in[2];
    const float* W2 = (const float*)d_in[3];
    const float* b2 = (const float*)d_in[4];
    const float* W3 = (const float*)d_in[5];
    const float* b3 = (const float*)d_in[6];
    const float* Wc = (const float*)d_in[7];
    const float* bc = (const float*)d_in[8];
    const int* ei = (const int*)d_in[9];
    const int* batch = (const int*)d_in[10];
    const int* row = ei;
    const int* col = ei + N_EDGES;
    float* out = (float*)d_out;

    char* ws = (char*)d_ws;
    size_t off = 0;
    auto alloc = [&](size_t bytes) -> void* {
        off = (off + 255) & ~(size_t)255;
        void* p = ws + off;
        off += bytes;
        return p;
    };

    int* counts = (int*)alloc((size_t)N_NODES * 4);
    int* offsets = (int*)alloc((size_t)(N_NODES + 1) * 4);
    int* cursor = (int*)alloc((size_t)N_NODES * 4);
    int* chunksums = (int*)alloc(256 * 4);
    float* dis = (float*)alloc((size_t)N_NODES * 4);
    int* csr_src = (int*)alloc((size_t)N_EDGES * 4);
    float* csr_w = (float*)alloc((size_t)N_EDGES * 4);
    float* aggx = (float*)alloc((size_t)N_NODES * 3 * 4);
    float* bufA = (float*)alloc((size_t)N_NODES * C1 * 4); // h1; then h2 (first half) + h3 (second half)
    float* bufB = (float*)alloc((size_t)N_NODES * C2 * 4); // m2; then m3

    float* h1 = bufA;
    float* m2 = bufB;
    float* h2 = bufA;                       // overwrites h1 (safe: h1 consumed by gemm2)
    float* m3 = bufB;                       // overwrites m2 (safe: m2 consumed by aggregate)
    float* h3 = bufA + (size_t)N_NODES * C2; // second half of bufA

    hipMemsetAsync(counts, 0, (size_t)N_NODES * 4, stream);
    count_edges<<<(N_EDGES + 255) / 256, 256, 0, stream>>>(col, counts);
    compute_dis<<<(N_NODES + 255) / 256, 256, 0, stream>>>(counts, dis);
    int nchunks = (N_NODES + 255) / 256;
    scan_chunks<<<nchunks, 256, 0, stream>>>(counts, offsets, chunksums);
    scan_sums<<<1, 256, 0, stream>>>(chunksums, nchunks);
    finalize_offsets<<<(N_NODES + 255) / 256, 256, 0, stream>>>(offsets, chunksums);
    init_cursor<<<(N_NODES + 255) / 256, 256, 0, stream>>>(offsets, cursor);
    scatter_edges<<<(N_EDGES + 255) / 256, 256, 0, stream>>>(row, col, dis, cursor, csr_src, csr_w);

    agg_feat3<<<(N_NODES + 255) / 256, 256, 0, stream>>>(x, offsets, csr_src, csr_w, dis, aggx);
    layer1<<<N_NODES, 256, 0, stream>>>(aggx, W1, b1, h1);

    dim3 g2((N_NODES + 63) / 64, C2 / 64);
    gemm_nn<C1><<<g2, 256, 0, stream>>>(h1, W2, m2, N_NODES, C2);
    aggregate<C2><<<N_NODES, C2, 0, stream>>>(m2, offsets, csr_src, csr_w, dis, b2, h2);

    dim3 g3((N_NODES + 63) / 64, C3 / 64);
    gemm_nn<C2><<<g3, 256, 0, stream>>>(h2, W3, m3, N_NODES, C3);
    aggregate<C3><<<N_NODES, C3, 0, stream>>>(m3, offsets, csr_src, csr_w, dis, b3, h3);

    pool_head<<<NGRAPH, C3, 0, stream>>>(h3, batch, Wc, bc, out);
}

// Round 2
// 562.601 us; speedup vs baseline: 1.4758x; 1.4758x over previous
//
#include <hip/hip_runtime.h>
#include <hip/hip_bf16.h>
#include <math.h>

#define N_NODES 50000
#define N_EDGES 800000
#define NFEAT 3
#define C1 512
#define C2 256
#define C3 128
#define NGRAPH 100
#define NCLS 2

typedef short bh8 __attribute__((ext_vector_type(8)));   // 8 bf16 bit-patterns (4 VGPRs)
typedef float f32x4 __attribute__((ext_vector_type(4))); // MFMA accumulator

__device__ __forceinline__ short f2bf(float x) {
    __hip_bfloat16 h = __float2bfloat16(x);
    return *reinterpret_cast<short*>(&h);
}
__device__ __forceinline__ float bflo(unsigned int u) { return __uint_as_float(u << 16); }
__device__ __forceinline__ float bfhi(unsigned int u) { return __uint_as_float(u & 0xffff0000u); }

// ---------------- degree / normalization ----------------

__global__ void count_edges(const int* __restrict__ col, int* __restrict__ counts) {
    int e = blockIdx.x * blockDim.x + threadIdx.x;
    if (e < N_EDGES) atomicAdd(&counts[col[e]], 1);
}

__global__ void compute_dis(const int* __restrict__ counts, float* __restrict__ dis) {
    int i = blockIdx.x * blockDim.x + threadIdx.x;
    if (i < N_NODES) dis[i] = rsqrtf((float)(counts[i] + 1)); // +1 self loop; deg>=1 always
}

// ---------------- CSR build: 2-level scan + scatter ----------------

__global__ void scan_chunks(const int* __restrict__ counts, int* __restrict__ offsets,
                            int* __restrict__ chunksums) {
    __shared__ int s[256];
    int b = blockIdx.x, t = threadIdx.x;
    int i = b * 256 + t;
    int v = (i < N_NODES) ? counts[i] : 0;
    s[t] = v;
    __syncthreads();
    for (int d = 1; d < 256; d <<= 1) {
        int add = (t >= d) ? s[t - d] : 0;
        __syncthreads();
        s[t] += add;
        __syncthreads();
    }
    if (i < N_NODES) offsets[i + 1] = s[t];
    if (t == 255) chunksums[b] = s[255];
}

__global__ void scan_sums(int* __restrict__ chunksums, int nchunks) {
    __shared__ int s[256];
    int t = threadIdx.x;
    int v = (t < nchunks) ? chunksums[t] : 0;
    s[t] = v;
    __syncthreads();
    for (int d = 1; d < 256; d <<= 1) {
        int add = (t >= d) ? s[t - d] : 0;
        __syncthreads();
        s[t] += add;
        __syncthreads();
    }
    if (t < nchunks) chunksums[t] = (t == 0) ? 0 : s[t - 1];
}

__global__ void finalize_offsets(int* __restrict__ offsets, const int* __restrict__ chunkoffs) {
    int i = blockIdx.x * blockDim.x + threadIdx.x;
    if (i < N_NODES) offsets[i + 1] += chunkoffs[i / 256];
    if (i == 0) offsets[0] = 0;
}

__global__ void init_cursor(const int* __restrict__ offsets, int* __restrict__ cursor) {
    int i = blockIdx.x * blockDim.x + threadIdx.x;
    if (i < N_NODES) cursor[i] = offsets[i];
}

__global__ void scatter_edges(const int* __restrict__ rowi, const int* __restrict__ coli,
                              const float* __restrict__ dis, int* __restrict__ cursor,
                              int* __restrict__ csr_src, float* __restrict__ csr_w) {
    int e = blockIdx.x * blockDim.x + threadIdx.x;
    if (e < N_EDGES) {
        int r = rowi[e], c = coli[e];
        int p = atomicAdd(&cursor[c], 1);
        csr_src[p] = r;
        csr_w[p] = dis[r] * dis[c];
    }
}

// ---------------- weight transpose + bf16 cast: W [K][Nn] f32 -> Wt [Nn][K] bf16 ----------------

__global__ void transp_bf16(const float* __restrict__ W, short* __restrict__ Wt, int K, int Nn) {
    int idx = blockIdx.x * 256 + threadIdx.x;
    if (idx < K * Nn) {
        int n = idx / K, k = idx % K;
        Wt[idx] = f2bf(W[k * Nn + n]);
    }
}

// ---------------- layer 1: aggregate 3 feats, then tiny GEMM (writes bf16) ----------------

__global__ void agg_feat3(const float* __restrict__ x, const int* __restrict__ offsets,
                          const int* __restrict__ csr_src, const float* __restrict__ csr_w,
                          const float* __restrict__ dis, float* __restrict__ aggx) {
    int i = blockIdx.x * blockDim.x + threadIdx.x;
    if (i >= N_NODES) return;
    float d = dis[i];
    float ws = d * d;
    float a0 = ws * x[i * 3 + 0], a1 = ws * x[i * 3 + 1], a2 = ws * x[i * 3 + 2];
    int s = offsets[i], e = offsets[i + 1];
    for (int p = s; p < e; ++p) {
        int r = csr_src[p];
        float w = csr_w[p];
        a0 += w * x[r * 3 + 0];
        a1 += w * x[r * 3 + 1];
        a2 += w * x[r * 3 + 2];
    }
    aggx[i * 3 + 0] = a0; aggx[i * 3 + 1] = a1; aggx[i * 3 + 2] = a2;
}

__global__ void layer1(const float* __restrict__ aggx, const float* __restrict__ W1,
                       const float* __restrict__ b1, short* __restrict__ h1) {
    int i = blockIdx.x;
    int t = threadIdx.x; // 256 threads, 2 channels each
    float a0 = aggx[i * 3 + 0], a1 = aggx[i * 3 + 1], a2 = aggx[i * 3 + 2];
    int j0 = 2 * t, j1 = 2 * t + 1;
    float v0 = fmaxf(a0 * W1[j0] + a1 * W1[C1 + j0] + a2 * W1[2 * C1 + j0] + b1[j0], 0.f);
    float v1 = fmaxf(a0 * W1[j1] + a1 * W1[C1 + j1] + a2 * W1[2 * C1 + j1] + b1[j1], 0.f);
    unsigned int pk = (unsigned int)(unsigned short)f2bf(v0) |
                      ((unsigned int)(unsigned short)f2bf(v1) << 16);
    ((unsigned int*)h1)[(size_t)i * (C1 / 2) + t] = pk;
}

// ---------------- bf16 MFMA GEMM: C[M x Nn] = A[M x K] * Bt^T, Bt is [Nn][K] bf16 ----------------
// Tile 128x64, BK=32, 256 threads = 4 waves in 2x2; each wave does 64x32 (4x2 mfma tiles).
// Fragment layouts (HW-verified): A/B frag elem = [lane&15][quad*8+j]; C/D col=lane&15, row=quad*4+reg.

template <int K>
__global__ __launch_bounds__(256, 2) void gemm_bf16(const short* __restrict__ A,
                                                    const short* __restrict__ Bt,
                                                    short* __restrict__ Cmat, int M, int Nn) {
    __shared__ short As[128 * 32];
    __shared__ short Bs[64 * 32];
    int bm = blockIdx.x * 128, bn = blockIdx.y * 64;
    int t = threadIdx.x;
    int wave = t >> 6, lane = t & 63, quad = lane >> 4, l16 = lane & 15;
    int wm = (wave >> 1) * 64, wn = (wave & 1) * 32;
    f32x4 acc[4][2] = {};

    int ar = t >> 1, ak = (t & 1) * 16;       // A: 128 rows x 32 cols, 32B per thread
    int br = t >> 2, bk = (t & 3) * 8;        // B: 64 rows x 32 cols, 16B per thread
    int agr = bm + ar; if (agr > M - 1) agr = M - 1; // clamp: rows >= M never stored
    const short* aptr = A + (size_t)agr * K + ak;
    const short* bptr = Bt + (size_t)(bn + br) * K + bk;

    for (int k0 = 0; k0 < K; k0 += 32) {
        *(bh8*)&As[ar * 32 + ak]     = *(const bh8*)(aptr + k0);
        *(bh8*)&As[ar * 32 + ak + 8] = *(const bh8*)(aptr + k0 + 8);
        *(bh8*)&Bs[br * 32 + bk]     = *(const bh8*)(bptr + k0);
        __syncthreads();
        bh8 af[4], bf[2];
#pragma unroll
        for (int mt = 0; mt < 4; ++mt)
            af[mt] = *(const bh8*)&As[(wm + mt * 16 + l16) * 32 + quad * 8];
#pragma unroll
        for (int nt = 0; nt < 2; ++nt)
            bf[nt] = *(const bh8*)&Bs[(wn + nt * 16 + l16) * 32 + quad * 8];
#pragma unroll
        for (int mt = 0; mt < 4; ++mt)
#pragma unroll
            for (int nt = 0; nt < 2; ++nt)
                acc[mt][nt] = __builtin_amdgcn_mfma_f32_16x16x32_bf16(af[mt], bf[nt], acc[mt][nt], 0, 0, 0);
        __syncthreads();
    }

#pragma unroll
    for (int mt = 0; mt < 4; ++mt)
#pragma unroll
        for (int nt = 0; nt < 2; ++nt) {
            int colc = bn + wn + nt * 16 + l16;
#pragma unroll
            for (int r = 0; r < 4; ++r) {
                int rowc = bm + wm + mt * 16 + quad * 4 + r;
                if (rowc < M) Cmat[(size_t)rowc * Nn + colc] = f2bf(acc[mt][nt][r]);
            }
        }
}

// ---------------- aggregation over CSR (bf16 messages), fused bias + relu ----------------

template <int C, bool OUTBF>
__global__ void aggregate_bf(const short* __restrict__ m, const int* __restrict__ offsets,
                             const int* __restrict__ csr_src, const float* __restrict__ csr_w,
                             const float* __restrict__ dis, const float* __restrict__ bias,
                             void* __restrict__ out) {
    int i = blockIdx.x;
    int t = threadIdx.x; // C/2 threads, 2 channels each
    float d = dis[i];
    float ws = d * d;
    unsigned int v = ((const unsigned int*)(m + (size_t)i * C))[t];
    float acc0 = ws * bflo(v), acc1 = ws * bfhi(v);
    int s = offsets[i], e = offsets[i + 1];
    for (int p = s; p < e; ++p) {
        int r = csr_src[p];
        float w = csr_w[p];
        unsigned int u = ((const unsigned int*)(m + (size_t)r * C))[t];
        acc0 += w * bflo(u);
        acc1 += w * bfhi(u);
    }
    acc0 = fmaxf(acc0 + bias[2 * t], 0.f);
    acc1 = fmaxf(acc1 + bias[2 * t + 1], 0.f);
    if (OUTBF) {
        unsigned int pk = (unsigned int)(unsigned short)f2bf(acc0) |
                          ((unsigned int)(unsigned short)f2bf(acc1) << 16);
        ((unsigned int*)out)[(size_t)i * (C / 2) + t] = pk;
    } else {
        ((float2*)out)[(size_t)i * (C / 2) + t] = make_float2(acc0, acc1);
    }
}

// ---------------- mean pool per graph + linear head + log_softmax ----------------

__global__ void pool_head(const float* __restrict__ h3, const int* __restrict__ batch,
                          const float* __restrict__ Wc, const float* __restrict__ bc,
                          float* __restrict__ outp) {
    int g = blockIdx.x;
    int t = threadIdx.x; // 128 threads = C3
    int lo = 0, hi = N_NODES;
    while (lo < hi) { int mid = (lo + hi) >> 1; if (batch[mid] < g) lo = mid + 1; else hi = mid; }
    int start = lo;
    hi = N_NODES;
    while (lo < hi) { int mid = (lo + hi) >> 1; if (batch[mid] < g + 1) lo = mid + 1; else hi = mid; }
    int end = lo;
    float sum = 0.f;
    for (int i = start; i < end; ++i) sum += h3[(size_t)i * C3 + t];
    float cnt = (float)(end - start);
    float pooled = sum / fmaxf(cnt, 1.f);
    float p0 = pooled * Wc[t * 2 + 0];
    float p1 = pooled * Wc[t * 2 + 1];
#pragma unroll
    for (int o = 32; o > 0; o >>= 1) {
        p0 += __shfl_down(p0, o);
        p1 += __shfl_down(p1, o);
    }
    __shared__ float r0[2], r1[2];
    int wid = t >> 6, lane = t & 63;
    if (lane == 0) { r0[wid] = p0; r1[wid] = p1; }
    __syncthreads();
    if (t == 0) {
        float l0 = r0[0] + r0[1] + bc[0];
        float l1 = r1[0] + r1[1] + bc[1];
        float mx = fmaxf(l0, l1);
        float lse = mx + logf(expf(l0 - mx) + expf(l1 - mx));
        outp[g * 2 + 0] = l0 - lse;
        outp[g * 2 + 1] = l1 - lse;
    }
}

// ---------------- launch ----------------

extern "C" void kernel_launch(void* const* d_in, const int* in_sizes, int n_in,
                              void* d_out, int out_size, void* d_ws, size_t ws_size,
                              hipStream_t stream) {
    const float* x = (const float*)d_in[0];
    const float* W1 = (const float*)d_in[1];
    const float* b1 = (const float*)d_in[2];
    const float* W2 = (const float*)d_in[3];
    const float* b2 = (const float*)d_in[4];
    const float* W3 = (const float*)d_in[5];
    const float* b3 = (const float*)d_in[6];
    const float* Wc = (const float*)d_in[7];
    const float* bc = (const float*)d_in[8];
    const int* ei = (const int*)d_in[9];
    const int* batch = (const int*)d_in[10];
    const int* row = ei;
    const int* col = ei + N_EDGES;
    float* out = (float*)d_out;

    char* ws = (char*)d_ws;
    size_t off = 0;
    auto alloc = [&](size_t bytes) -> void* {
        off = (off + 255) & ~(size_t)255;
        void* p = ws + off;
        off += bytes;
        return p;
    };

    int* counts = (int*)alloc((size_t)N_NODES * 4);
    int* offsets = (int*)alloc((size_t)(N_NODES + 1) * 4);
    int* cursor = (int*)alloc((size_t)N_NODES * 4);
    int* chunksums = (int*)alloc(256 * 4);
    float* dis = (float*)alloc((size_t)N_NODES * 4);
    int* csr_src = (int*)alloc((size_t)N_EDGES * 4);
    float* csr_w = (float*)alloc((size_t)N_EDGES * 4);
    float* aggx = (float*)alloc((size_t)N_NODES * 3 * 4);
    short* W2t = (short*)alloc((size_t)C1 * C2 * 2);   // [C2][C1] bf16
    short* W3t = (short*)alloc((size_t)C2 * C3 * 2);   // [C3][C2] bf16
    short* h1 = (short*)alloc((size_t)N_NODES * C1 * 2);
    short* m2 = (short*)alloc((size_t)N_NODES * C2 * 2);
    short* h2 = (short*)alloc((size_t)N_NODES * C2 * 2);
    short* m3 = (short*)alloc((size_t)N_NODES * C3 * 2);
    float* h3 = (float*)alloc((size_t)N_NODES * C3 * 4);

    hipMemsetAsync(counts, 0, (size_t)N_NODES * 4, stream);
    count_edges<<<(N_EDGES + 255) / 256, 256, 0, stream>>>(col, counts);
    compute_dis<<<(N_NODES + 255) / 256, 256, 0, stream>>>(counts, dis);
    int nchunks = (N_NODES + 255) / 256;
    scan_chunks<<<nchunks, 256, 0, stream>>>(counts, offsets, chunksums);
    scan_sums<<<1, 256, 0, stream>>>(chunksums, nchunks);
    finalize_offsets<<<(N_NODES + 255) / 256, 256, 0, stream>>>(offsets, chunksums);
    init_cursor<<<(N_NODES + 255) / 256, 256, 0, stream>>>(offsets, cursor);
    scatter_edges<<<(N_EDGES + 255) / 256, 256, 0, stream>>>(row, col, dis, cursor, csr_src, csr_w);

    transp_bf16<<<(C1 * C2 + 255) / 256, 256, 0, stream>>>(W2, W2t, C1, C2);
    transp_bf16<<<(C2 * C3 + 255) / 256, 256, 0, stream>>>(W3, W3t, C2, C3);

    agg_feat3<<<(N_NODES + 255) / 256, 256, 0, stream>>>(x, offsets, csr_src, csr_w, dis, aggx);
    layer1<<<N_NODES, C1 / 2, 0, stream>>>(aggx, W1, b1, h1);

    dim3 g2((N_NODES + 127) / 128, C2 / 64);
    gemm_bf16<C1><<<g2, 256, 0, stream>>>(h1, W2t, m2, N_NODES, C2);
    aggregate_bf<C2, true><<<N_NODES, C2 / 2, 0, stream>>>(m2, offsets, csr_src, csr_w, dis, b2, h2);

    dim3 g3((N_NODES + 127) / 128, C3 / 64);
    gemm_bf16<C2><<<g3, 256, 0, stream>>>(h2, W3t, m3, N_NODES, C3);
    aggregate_bf<C3, false><<<N_NODES, C3 / 2, 0, stream>>>(m3, offsets, csr_src, csr_w, dis, b3, h3);

    pool_head<<<NGRAPH, C3, 0, stream>>>(h3, batch, Wc, bc, out);
}

// Round 3
// 521.102 us; speedup vs baseline: 1.5933x; 1.0796x over previous
//
#include <hip/hip_runtime.h>
#include <hip/hip_bf16.h>
#include <math.h>

#define N_NODES 50000
#define N_EDGES 800000
#define NFEAT 3
#define C1 512
#define C2 256
#define C3 128
#define NGRAPH 100
#define NCLS 2

typedef short bh8 __attribute__((ext_vector_type(8)));   // 8 bf16 bit-patterns (4 VGPRs)
typedef float f32x4 __attribute__((ext_vector_type(4))); // MFMA accumulator

__device__ __forceinline__ short f2bf(float x) {
    __hip_bfloat16 h = __float2bfloat16(x);
    return *reinterpret_cast<short*>(&h);
}
__device__ __forceinline__ float bflo(unsigned int u) { return __uint_as_float(u << 16); }
__device__ __forceinline__ float bfhi(unsigned int u) { return __uint_as_float(u & 0xffff0000u); }

// ---------------- degree / normalization ----------------

__global__ void count_edges(const int* __restrict__ col, int* __restrict__ counts) {
    int e = blockIdx.x * blockDim.x + threadIdx.x;
    if (e < N_EDGES) atomicAdd(&counts[col[e]], 1);
}

__global__ void compute_dis(const int* __restrict__ counts, float* __restrict__ dis) {
    int i = blockIdx.x * blockDim.x + threadIdx.x;
    if (i < N_NODES) dis[i] = rsqrtf((float)(counts[i] + 1)); // +1 self loop; deg>=1 always
}

// ---------------- CSR build: 2-level scan + scatter ----------------

__global__ void scan_chunks(const int* __restrict__ counts, int* __restrict__ offsets,
                            int* __restrict__ chunksums) {
    __shared__ int s[256];
    int b = blockIdx.x, t = threadIdx.x;
    int i = b * 256 + t;
    int v = (i < N_NODES) ? counts[i] : 0;
    s[t] = v;
    __syncthreads();
    for (int d = 1; d < 256; d <<= 1) {
        int add = (t >= d) ? s[t - d] : 0;
        __syncthreads();
        s[t] += add;
        __syncthreads();
    }
    if (i < N_NODES) offsets[i + 1] = s[t];
    if (t == 255) chunksums[b] = s[255];
}

__global__ void scan_sums(int* __restrict__ chunksums, int nchunks) {
    __shared__ int s[256];
    int t = threadIdx.x;
    int v = (t < nchunks) ? chunksums[t] : 0;
    s[t] = v;
    __syncthreads();
    for (int d = 1; d < 256; d <<= 1) {
        int add = (t >= d) ? s[t - d] : 0;
        __syncthreads();
        s[t] += add;
        __syncthreads();
    }
    if (t < nchunks) chunksums[t] = (t == 0) ? 0 : s[t - 1];
}

__global__ void finalize_offsets(int* __restrict__ offsets, const int* __restrict__ chunkoffs) {
    int i = blockIdx.x * blockDim.x + threadIdx.x;
    if (i < N_NODES) offsets[i + 1] += chunkoffs[i / 256];
    if (i == 0) offsets[0] = 0;
}

__global__ void init_cursor(const int* __restrict__ offsets, int* __restrict__ cursor) {
    int i = blockIdx.x * blockDim.x + threadIdx.x;
    if (i < N_NODES) cursor[i] = offsets[i];
}

__global__ void scatter_edges(const int* __restrict__ rowi, const int* __restrict__ coli,
                              const float* __restrict__ dis, int* __restrict__ cursor,
                              int* __restrict__ csr_src, float* __restrict__ csr_w) {
    int e = blockIdx.x * blockDim.x + threadIdx.x;
    if (e < N_EDGES) {
        int r = rowi[e], c = coli[e];
        int p = atomicAdd(&cursor[c], 1);
        csr_src[p] = r;
        csr_w[p] = dis[r] * dis[c];
    }
}

// ---------------- weight transpose + bf16 cast: W [K][Nn] f32 -> Wt [Nn][K] bf16 ----------------

__global__ void transp_bf16(const float* __restrict__ W, short* __restrict__ Wt, int K, int Nn) {
    int idx = blockIdx.x * 256 + threadIdx.x;
    if (idx < K * Nn) {
        int n = idx / K, k = idx % K;
        Wt[idx] = f2bf(W[k * Nn + n]);
    }
}

// ---------------- layer 1: aggregate 3 feats, then tiny GEMM (writes bf16) ----------------

__global__ void agg_feat3(const float* __restrict__ x, const int* __restrict__ offsets,
                          const int* __restrict__ csr_src, const float* __restrict__ csr_w,
                          const float* __restrict__ dis, float* __restrict__ aggx) {
    int i = blockIdx.x * blockDim.x + threadIdx.x;
    if (i >= N_NODES) return;
    float d = dis[i];
    float ws = d * d;
    float a0 = ws * x[i * 3 + 0], a1 = ws * x[i * 3 + 1], a2 = ws * x[i * 3 + 2];
    int s = offsets[i], e = offsets[i + 1];
    for (int p = s; p < e; ++p) {
        int r = csr_src[p];
        float w = csr_w[p];
        a0 += w * x[r * 3 + 0];
        a1 += w * x[r * 3 + 1];
        a2 += w * x[r * 3 + 2];
    }
    aggx[i * 3 + 0] = a0; aggx[i * 3 + 1] = a1; aggx[i * 3 + 2] = a2;
}

__global__ void layer1(const float* __restrict__ aggx, const float* __restrict__ W1,
                       const float* __restrict__ b1, short* __restrict__ h1) {
    int i = blockIdx.x;
    int t = threadIdx.x; // 256 threads, 2 channels each
    float a0 = aggx[i * 3 + 0], a1 = aggx[i * 3 + 1], a2 = aggx[i * 3 + 2];
    int j0 = 2 * t, j1 = 2 * t + 1;
    float v0 = fmaxf(a0 * W1[j0] + a1 * W1[C1 + j0] + a2 * W1[2 * C1 + j0] + b1[j0], 0.f);
    float v1 = fmaxf(a0 * W1[j1] + a1 * W1[C1 + j1] + a2 * W1[2 * C1 + j1] + b1[j1], 0.f);
    unsigned int pk = (unsigned int)(unsigned short)f2bf(v0) |
                      ((unsigned int)(unsigned short)f2bf(v1) << 16);
    ((unsigned int*)h1)[(size_t)i * (C1 / 2) + t] = pk;
}

// ---------------- bf16 MFMA GEMM: C[M x Nn] = A[M x K] * Bt^T, Bt is [Nn][K] bf16 ----------------

template <int K>
__global__ __launch_bounds__(256, 2) void gemm_bf16(const short* __restrict__ A,
                                                    const short* __restrict__ Bt,
                                                    short* __restrict__ Cmat, int M, int Nn) {
    __shared__ short As[128 * 32];
    __shared__ short Bs[64 * 32];
    int bm = blockIdx.x * 128, bn = blockIdx.y * 64;
    int t = threadIdx.x;
    int wave = t >> 6, lane = t & 63, quad = lane >> 4, l16 = lane & 15;
    int wm = (wave >> 1) * 64, wn = (wave & 1) * 32;
    f32x4 acc[4][2] = {};

    int ar = t >> 1, ak = (t & 1) * 16;       // A: 128 rows x 32 cols, 32B per thread
    int br = t >> 2, bk = (t & 3) * 8;        // B: 64 rows x 32 cols, 16B per thread
    int agr = bm + ar; if (agr > M - 1) agr = M - 1; // clamp: rows >= M never stored
    const short* aptr = A + (size_t)agr * K + ak;
    const short* bptr = Bt + (size_t)(bn + br) * K + bk;

    for (int k0 = 0; k0 < K; k0 += 32) {
        *(bh8*)&As[ar * 32 + ak]     = *(const bh8*)(aptr + k0);
        *(bh8*)&As[ar * 32 + ak + 8] = *(const bh8*)(aptr + k0 + 8);
        *(bh8*)&Bs[br * 32 + bk]     = *(const bh8*)(bptr + k0);
        __syncthreads();
        bh8 af[4], bf[2];
#pragma unroll
        for (int mt = 0; mt < 4; ++mt)
            af[mt] = *(const bh8*)&As[(wm + mt * 16 + l16) * 32 + quad * 8];
#pragma unroll
        for (int nt = 0; nt < 2; ++nt)
            bf[nt] = *(const bh8*)&Bs[(wn + nt * 16 + l16) * 32 + quad * 8];
#pragma unroll
        for (int mt = 0; mt < 4; ++mt)
#pragma unroll
            for (int nt = 0; nt < 2; ++nt)
                acc[mt][nt] = __builtin_amdgcn_mfma_f32_16x16x32_bf16(af[mt], bf[nt], acc[mt][nt], 0, 0, 0);
        __syncthreads();
    }

#pragma unroll
    for (int mt = 0; mt < 4; ++mt)
#pragma unroll
        for (int nt = 0; nt < 2; ++nt) {
            int colc = bn + wn + nt * 16 + l16;
#pragma unroll
            for (int r = 0; r < 4; ++r) {
                int rowc = bm + wm + mt * 16 + quad * 4 + r;
                if (rowc < M) Cmat[(size_t)rowc * Nn + colc] = f2bf(acc[mt][nt][r]);
            }
        }
}

// ---------------- aggregation over CSR (bf16 messages), fused bias + relu ----------------

template <int C>
__global__ void aggregate_bf(const short* __restrict__ m, const int* __restrict__ offsets,
                             const int* __restrict__ csr_src, const float* __restrict__ csr_w,
                             const float* __restrict__ dis, const float* __restrict__ bias,
                             short* __restrict__ out) {
    int i = blockIdx.x;
    int t = threadIdx.x; // C/2 threads, 2 channels each
    float d = dis[i];
    float ws = d * d;
    unsigned int v = ((const unsigned int*)(m + (size_t)i * C))[t];
    float acc0 = ws * bflo(v), acc1 = ws * bfhi(v);
    int s = offsets[i], e = offsets[i + 1];
    for (int p = s; p < e; ++p) {
        int r = csr_src[p];
        float w = csr_w[p];
        unsigned int u = ((const unsigned int*)(m + (size_t)r * C))[t];
        acc0 += w * bflo(u);
        acc1 += w * bfhi(u);
    }
    acc0 = fmaxf(acc0 + bias[2 * t], 0.f);
    acc1 = fmaxf(acc1 + bias[2 * t + 1], 0.f);
    unsigned int pk = (unsigned int)(unsigned short)f2bf(acc0) |
                      ((unsigned int)(unsigned short)f2bf(acc1) << 16);
    ((unsigned int*)out)[(size_t)i * (C / 2) + t] = pk;
}

// ---- layer-3 aggregation with fused mean-pool: atomicAdd relu'd node vec into pooled[g][c] ----

template <int C>
__global__ void aggregate_pool(const short* __restrict__ m, const int* __restrict__ offsets,
                               const int* __restrict__ csr_src, const float* __restrict__ csr_w,
                               const float* __restrict__ dis, const float* __restrict__ bias,
                               const int* __restrict__ batch, float* __restrict__ pooled) {
    int i = blockIdx.x;
    int t = threadIdx.x; // C/2 threads, 2 channels each
    float d = dis[i];
    float ws = d * d;
    unsigned int v = ((const unsigned int*)(m + (size_t)i * C))[t];
    float acc0 = ws * bflo(v), acc1 = ws * bfhi(v);
    int s = offsets[i], e = offsets[i + 1];
    for (int p = s; p < e; ++p) {
        int r = csr_src[p];
        float w = csr_w[p];
        unsigned int u = ((const unsigned int*)(m + (size_t)r * C))[t];
        acc0 += w * bflo(u);
        acc1 += w * bfhi(u);
    }
    acc0 = fmaxf(acc0 + bias[2 * t], 0.f);
    acc1 = fmaxf(acc1 + bias[2 * t + 1], 0.f);
    int g = batch[i];
    atomicAdd(&pooled[(size_t)g * C + 2 * t], acc0);
    atomicAdd(&pooled[(size_t)g * C + 2 * t + 1], acc1);
}

// ---------------- head: mean-divide + linear + log_softmax ----------------

__global__ void finalize_head(const float* __restrict__ pooled, const int* __restrict__ batch,
                              const float* __restrict__ Wc, const float* __restrict__ bc,
                              float* __restrict__ outp) {
    int g = blockIdx.x;
    int t = threadIdx.x; // 128 threads = C3
    __shared__ int seg[2];
    if (t < 2) {
        int target = g + t;
        int lo = 0, hi = N_NODES;
        while (lo < hi) { int mid = (lo + hi) >> 1; if (batch[mid] < target) lo = mid + 1; else hi = mid; }
        seg[t] = lo;
    }
    __syncthreads();
    float cnt = (float)(seg[1] - seg[0]);
    float pv = pooled[(size_t)g * C3 + t] / fmaxf(cnt, 1.f);
    float p0 = pv * Wc[t * 2 + 0];
    float p1 = pv * Wc[t * 2 + 1];
#pragma unroll
    for (int o = 32; o > 0; o >>= 1) {
        p0 += __shfl_down(p0, o);
        p1 += __shfl_down(p1, o);
    }
    __shared__ float r0[2], r1[2];
    int wid = t >> 6, lane = t & 63;
    if (lane == 0) { r0[wid] = p0; r1[wid] = p1; }
    __syncthreads();
    if (t == 0) {
        float l0 = r0[0] + r0[1] + bc[0];
        float l1 = r1[0] + r1[1] + bc[1];
        float mx = fmaxf(l0, l1);
        float lse = mx + logf(expf(l0 - mx) + expf(l1 - mx));
        outp[g * 2 + 0] = l0 - lse;
        outp[g * 2 + 1] = l1 - lse;
    }
}

// ---------------- launch ----------------

extern "C" void kernel_launch(void* const* d_in, const int* in_sizes, int n_in,
                              void* d_out, int out_size, void* d_ws, size_t ws_size,
                              hipStream_t stream) {
    const float* x = (const float*)d_in[0];
    const float* W1 = (const float*)d_in[1];
    const float* b1 = (const float*)d_in[2];
    const float* W2 = (const float*)d_in[3];
    const float* b2 = (const float*)d_in[4];
    const float* W3 = (const float*)d_in[5];
    const float* b3 = (const float*)d_in[6];
    const float* Wc = (const float*)d_in[7];
    const float* bc = (const float*)d_in[8];
    const int* ei = (const int*)d_in[9];
    const int* batch = (const int*)d_in[10];
    const int* row = ei;
    const int* col = ei + N_EDGES;
    float* out = (float*)d_out;

    char* ws = (char*)d_ws;
    size_t off = 0;
    auto alloc = [&](size_t bytes) -> void* {
        off = (off + 255) & ~(size_t)255;
        void* p = ws + off;
        off += bytes;
        return p;
    };

    int* counts = (int*)alloc((size_t)N_NODES * 4);
    int* offsets = (int*)alloc((size_t)(N_NODES + 1) * 4);
    int* cursor = (int*)alloc((size_t)N_NODES * 4);
    int* chunksums = (int*)alloc(256 * 4);
    float* dis = (float*)alloc((size_t)N_NODES * 4);
    int* csr_src = (int*)alloc((size_t)N_EDGES * 4);
    float* csr_w = (float*)alloc((size_t)N_EDGES * 4);
    float* aggx = (float*)alloc((size_t)N_NODES * 3 * 4);
    short* W2t = (short*)alloc((size_t)C1 * C2 * 2);   // [C2][C1] bf16
    short* W3t = (short*)alloc((size_t)C2 * C3 * 2);   // [C3][C2] bf16
    short* h1 = (short*)alloc((size_t)N_NODES * C1 * 2);
    short* m2 = (short*)alloc((size_t)N_NODES * C2 * 2);
    short* h2 = (short*)alloc((size_t)N_NODES * C2 * 2);
    short* m3 = (short*)alloc((size_t)N_NODES * C3 * 2);
    float* pooled = (float*)alloc((size_t)NGRAPH * C3 * 4);

    hipMemsetAsync(counts, 0, (size_t)N_NODES * 4, stream);
    hipMemsetAsync(pooled, 0, (size_t)NGRAPH * C3 * 4, stream);
    count_edges<<<(N_EDGES + 255) / 256, 256, 0, stream>>>(col, counts);
    compute_dis<<<(N_NODES + 255) / 256, 256, 0, stream>>>(counts, dis);
    int nchunks = (N_NODES + 255) / 256;
    scan_chunks<<<nchunks, 256, 0, stream>>>(counts, offsets, chunksums);
    scan_sums<<<1, 256, 0, stream>>>(chunksums, nchunks);
    finalize_offsets<<<(N_NODES + 255) / 256, 256, 0, stream>>>(offsets, chunksums);
    init_cursor<<<(N_NODES + 255) / 256, 256, 0, stream>>>(offsets, cursor);
    scatter_edges<<<(N_EDGES + 255) / 256, 256, 0, stream>>>(row, col, dis, cursor, csr_src, csr_w);

    transp_bf16<<<(C1 * C2 + 255) / 256, 256, 0, stream>>>(W2, W2t, C1, C2);
    transp_bf16<<<(C2 * C3 + 255) / 256, 256, 0, stream>>>(W3, W3t, C2, C3);

    agg_feat3<<<(N_NODES + 255) / 256, 256, 0, stream>>>(x, offsets, csr_src, csr_w, dis, aggx);
    layer1<<<N_NODES, C1 / 2, 0, stream>>>(aggx, W1, b1, h1);

    dim3 g2((N_NODES + 127) / 128, C2 / 64);
    gemm_bf16<C1><<<g2, 256, 0, stream>>>(h1, W2t, m2, N_NODES, C2);
    aggregate_bf<C2><<<N_NODES, C2 / 2, 0, stream>>>(m2, offsets, csr_src, csr_w, dis, b2, h2);

    dim3 g3((N_NODES + 127) / 128, C3 / 64);
    gemm_bf16<C2><<<g3, 256, 0, stream>>>(h2, W3t, m3, N_NODES, C3);
    aggregate_pool<C3><<<N_NODES, C3 / 2, 0, stream>>>(m3, offsets, csr_src, csr_w, dis, b3, batch, pooled);

    finalize_head<<<NGRAPH, C3, 0, stream>>>(pooled, batch, Wc, bc, out);
}

// Round 4
// 375.217 us; speedup vs baseline: 2.2128x; 1.3888x over previous
//
#include <hip/hip_runtime.h>
#include <hip/hip_bf16.h>
#include <math.h>

#define N_NODES 50000
#define N_EDGES 800000
#define NFEAT 3
#define C1 512
#define C2 256
#define C3 128
#define NGRAPH 100
#define NCLS 2
#define PSPLIT 8

typedef short bh8 __attribute__((ext_vector_type(8)));   // 8 bf16 bit-patterns (4 VGPRs)
typedef float f32x4 __attribute__((ext_vector_type(4))); // MFMA accumulator

__device__ __forceinline__ short f2bf(float x) {
    __hip_bfloat16 h = __float2bfloat16(x);
    return *reinterpret_cast<short*>(&h);
}
__device__ __forceinline__ float bflo(unsigned int u) { return __uint_as_float(u << 16); }
__device__ __forceinline__ float bfhi(unsigned int u) { return __uint_as_float(u & 0xffff0000u); }

// ---------------- degree / normalization ----------------

__global__ void count_edges(const int* __restrict__ col, int* __restrict__ counts) {
    int e = blockIdx.x * blockDim.x + threadIdx.x;
    if (e < N_EDGES) atomicAdd(&counts[col[e]], 1);
}

__global__ void compute_dis(const int* __restrict__ counts, float* __restrict__ dis) {
    int i = blockIdx.x * blockDim.x + threadIdx.x;
    if (i < N_NODES) dis[i] = rsqrtf((float)(counts[i] + 1)); // +1 self loop; deg>=1 always
}

// ---------------- CSR build: 2-level scan + scatter ----------------

__global__ void scan_chunks(const int* __restrict__ counts, int* __restrict__ offsets,
                            int* __restrict__ chunksums) {
    __shared__ int s[256];
    int b = blockIdx.x, t = threadIdx.x;
    int i = b * 256 + t;
    int v = (i < N_NODES) ? counts[i] : 0;
    s[t] = v;
    __syncthreads();
    for (int d = 1; d < 256; d <<= 1) {
        int add = (t >= d) ? s[t - d] : 0;
        __syncthreads();
        s[t] += add;
        __syncthreads();
    }
    if (i < N_NODES) offsets[i + 1] = s[t];
    if (t == 255) chunksums[b] = s[255];
}

__global__ void scan_sums(int* __restrict__ chunksums, int nchunks) {
    __shared__ int s[256];
    int t = threadIdx.x;
    int v = (t < nchunks) ? chunksums[t] : 0;
    s[t] = v;
    __syncthreads();
    for (int d = 1; d < 256; d <<= 1) {
        int add = (t >= d) ? s[t - d] : 0;
        __syncthreads();
        s[t] += add;
        __syncthreads();
    }
    if (t < nchunks) chunksums[t] = (t == 0) ? 0 : s[t - 1];
}

__global__ void finalize_offsets(int* __restrict__ offsets, const int* __restrict__ chunkoffs) {
    int i = blockIdx.x * blockDim.x + threadIdx.x;
    if (i < N_NODES) offsets[i + 1] += chunkoffs[i / 256];
    if (i == 0) offsets[0] = 0;
}

__global__ void init_cursor(const int* __restrict__ offsets, int* __restrict__ cursor) {
    int i = blockIdx.x * blockDim.x + threadIdx.x;
    if (i < N_NODES) cursor[i] = offsets[i];
}

__global__ void scatter_edges(const int* __restrict__ rowi, const int* __restrict__ coli,
                              const float* __restrict__ dis, int* __restrict__ cursor,
                              int* __restrict__ csr_src, float* __restrict__ csr_w) {
    int e = blockIdx.x * blockDim.x + threadIdx.x;
    if (e < N_EDGES) {
        int r = rowi[e], c = coli[e];
        int p = atomicAdd(&cursor[c], 1);
        csr_src[p] = r;
        csr_w[p] = dis[r] * dis[c];
    }
}

// ---------------- weight transpose + bf16 cast: W [K][Nn] f32 -> Wt [Nn][K] bf16 ----------------

__global__ void transp_bf16(const float* __restrict__ W, short* __restrict__ Wt, int K, int Nn) {
    int idx = blockIdx.x * 256 + threadIdx.x;
    if (idx < K * Nn) {
        int n = idx / K, k = idx % K;
        Wt[idx] = f2bf(W[k * Nn + n]);
    }
}

// ---------------- layer 1: aggregate 3 feats, then tiny GEMM (writes bf16) ----------------

__global__ void agg_feat3(const float* __restrict__ x, const int* __restrict__ offsets,
                          const int* __restrict__ csr_src, const float* __restrict__ csr_w,
                          const float* __restrict__ dis, float* __restrict__ aggx) {
    int i = blockIdx.x * blockDim.x + threadIdx.x;
    if (i >= N_NODES) return;
    float d = dis[i];
    float ws = d * d;
    float a0 = ws * x[i * 3 + 0], a1 = ws * x[i * 3 + 1], a2 = ws * x[i * 3 + 2];
    int s = offsets[i], e = offsets[i + 1];
    int p = s;
    for (; p + 4 <= e; p += 4) {
        int r0 = csr_src[p], r1 = csr_src[p + 1], r2 = csr_src[p + 2], r3 = csr_src[p + 3];
        float w0 = csr_w[p], w1 = csr_w[p + 1], w2 = csr_w[p + 2], w3 = csr_w[p + 3];
        float3 v0 = *(const float3*)&x[r0 * 3];
        float3 v1 = *(const float3*)&x[r1 * 3];
        float3 v2 = *(const float3*)&x[r2 * 3];
        float3 v3 = *(const float3*)&x[r3 * 3];
        a0 += w0 * v0.x + w1 * v1.x + w2 * v2.x + w3 * v3.x;
        a1 += w0 * v0.y + w1 * v1.y + w2 * v2.y + w3 * v3.y;
        a2 += w0 * v0.z + w1 * v1.z + w2 * v2.z + w3 * v3.z;
    }
    for (; p < e; ++p) {
        int r = csr_src[p];
        float w = csr_w[p];
        a0 += w * x[r * 3 + 0];
        a1 += w * x[r * 3 + 1];
        a2 += w * x[r * 3 + 2];
    }
    aggx[i * 3 + 0] = a0; aggx[i * 3 + 1] = a1; aggx[i * 3 + 2] = a2;
}

__global__ void layer1(const float* __restrict__ aggx, const float* __restrict__ W1,
                       const float* __restrict__ b1, short* __restrict__ h1) {
    int i = blockIdx.x;
    int t = threadIdx.x; // 256 threads, 2 channels each
    float a0 = aggx[i * 3 + 0], a1 = aggx[i * 3 + 1], a2 = aggx[i * 3 + 2];
    int j0 = 2 * t, j1 = 2 * t + 1;
    float v0 = fmaxf(a0 * W1[j0] + a1 * W1[C1 + j0] + a2 * W1[2 * C1 + j0] + b1[j0], 0.f);
    float v1 = fmaxf(a0 * W1[j1] + a1 * W1[C1 + j1] + a2 * W1[2 * C1 + j1] + b1[j1], 0.f);
    unsigned int pk = (unsigned int)(unsigned short)f2bf(v0) |
                      ((unsigned int)(unsigned short)f2bf(v1) << 16);
    ((unsigned int*)h1)[(size_t)i * (C1 / 2) + t] = pk;
}

// ---------------- bf16 MFMA GEMM: C[M x Nn] = A[M x K] * Bt^T, Bt is [Nn][K] bf16 ----------------

template <int K>
__global__ __launch_bounds__(256, 2) void gemm_bf16(const short* __restrict__ A,
                                                    const short* __restrict__ Bt,
                                                    short* __restrict__ Cmat, int M, int Nn) {
    __shared__ short As[128 * 32];
    __shared__ short Bs[64 * 32];
    int bm = blockIdx.x * 128, bn = blockIdx.y * 64;
    int t = threadIdx.x;
    int wave = t >> 6, lane = t & 63, quad = lane >> 4, l16 = lane & 15;
    int wm = (wave >> 1) * 64, wn = (wave & 1) * 32;
    f32x4 acc[4][2] = {};

    int ar = t >> 1, ak = (t & 1) * 16;       // A: 128 rows x 32 cols, 32B per thread
    int br = t >> 2, bk = (t & 3) * 8;        // B: 64 rows x 32 cols, 16B per thread
    int agr = bm + ar; if (agr > M - 1) agr = M - 1; // clamp: rows >= M never stored
    const short* aptr = A + (size_t)agr * K + ak;
    const short* bptr = Bt + (size_t)(bn + br) * K + bk;

    for (int k0 = 0; k0 < K; k0 += 32) {
        *(bh8*)&As[ar * 32 + ak]     = *(const bh8*)(aptr + k0);
        *(bh8*)&As[ar * 32 + ak + 8] = *(const bh8*)(aptr + k0 + 8);
        *(bh8*)&Bs[br * 32 + bk]     = *(const bh8*)(bptr + k0);
        __syncthreads();
        bh8 af[4], bf[2];
#pragma unroll
        for (int mt = 0; mt < 4; ++mt)
            af[mt] = *(const bh8*)&As[(wm + mt * 16 + l16) * 32 + quad * 8];
#pragma unroll
        for (int nt = 0; nt < 2; ++nt)
            bf[nt] = *(const bh8*)&Bs[(wn + nt * 16 + l16) * 32 + quad * 8];
#pragma unroll
        for (int mt = 0; mt < 4; ++mt)
#pragma unroll
            for (int nt = 0; nt < 2; ++nt)
                acc[mt][nt] = __builtin_amdgcn_mfma_f32_16x16x32_bf16(af[mt], bf[nt], acc[mt][nt], 0, 0, 0);
        __syncthreads();
    }

#pragma unroll
    for (int mt = 0; mt < 4; ++mt)
#pragma unroll
        for (int nt = 0; nt < 2; ++nt) {
            int colc = bn + wn + nt * 16 + l16;
#pragma unroll
            for (int r = 0; r < 4; ++r) {
                int rowc = bm + wm + mt * 16 + quad * 4 + r;
                if (rowc < M) Cmat[(size_t)rowc * Nn + colc] = f2bf(acc[mt][nt][r]);
            }
        }
}

// ------- aggregation over CSR (bf16 messages), fused bias + relu, x4-unrolled edge loop -------

template <int C>
__global__ void aggregate_bf(const short* __restrict__ m, const int* __restrict__ offsets,
                             const int* __restrict__ csr_src, const float* __restrict__ csr_w,
                             const float* __restrict__ dis, const float* __restrict__ bias,
                             short* __restrict__ out) {
    int i = blockIdx.x;
    int t = threadIdx.x; // C/2 threads, 2 channels each
    float d = dis[i];
    float ws = d * d;
    const unsigned int* mu = (const unsigned int*)m;
    unsigned int v = mu[(size_t)i * (C / 2) + t];
    float acc0 = ws * bflo(v), acc1 = ws * bfhi(v);
    int s = offsets[i], e = offsets[i + 1];
    int p = s;
    for (; p + 4 <= e; p += 4) {
        int r0 = csr_src[p], r1 = csr_src[p + 1], r2 = csr_src[p + 2], r3 = csr_src[p + 3];
        float w0 = csr_w[p], w1 = csr_w[p + 1], w2 = csr_w[p + 2], w3 = csr_w[p + 3];
        unsigned int u0 = mu[(size_t)r0 * (C / 2) + t];
        unsigned int u1 = mu[(size_t)r1 * (C / 2) + t];
        unsigned int u2 = mu[(size_t)r2 * (C / 2) + t];
        unsigned int u3 = mu[(size_t)r3 * (C / 2) + t];
        acc0 += w0 * bflo(u0) + w1 * bflo(u1) + w2 * bflo(u2) + w3 * bflo(u3);
        acc1 += w0 * bfhi(u0) + w1 * bfhi(u1) + w2 * bfhi(u2) + w3 * bfhi(u3);
    }
    for (; p < e; ++p) {
        int r = csr_src[p];
        float w = csr_w[p];
        unsigned int u = mu[(size_t)r * (C / 2) + t];
        acc0 += w * bflo(u);
        acc1 += w * bfhi(u);
    }
    acc0 = fmaxf(acc0 + bias[2 * t], 0.f);
    acc1 = fmaxf(acc1 + bias[2 * t + 1], 0.f);
    unsigned int pk = (unsigned int)(unsigned short)f2bf(acc0) |
                      ((unsigned int)(unsigned short)f2bf(acc1) << 16);
    ((unsigned int*)out)[(size_t)i * (C / 2) + t] = pk;
}

// ---------------- two-stage mean pool: per-(graph,split) partial sums, few atomics ----------------

__global__ void pool_partial(const short* __restrict__ h3, const int* __restrict__ batch,
                             float* __restrict__ pooled) {
    int g = blockIdx.x, sp = blockIdx.y;
    int t = threadIdx.x; // 64 threads, 2 channels each (C3=128)
    __shared__ int seg[2];
    if (t < 2) {
        int target = g + t;
        int lo = 0, hi = N_NODES;
        while (lo < hi) { int mid = (lo + hi) >> 1; if (batch[mid] < target) lo = mid + 1; else hi = mid; }
        seg[t] = lo;
    }
    __syncthreads();
    int start = seg[0], end = seg[1];
    int len = end - start;
    int chunk = (len + PSPLIT - 1) / PSPLIT;
    int a = start + sp * chunk;
    int b = a + chunk; if (b > end) b = end;
    if (a >= b) return;
    const unsigned int* hu = (const unsigned int*)h3;
    float s0 = 0.f, s1 = 0.f;
    int i = a;
    for (; i + 4 <= b; i += 4) {
        unsigned int u0 = hu[(size_t)(i + 0) * (C3 / 2) + t];
        unsigned int u1 = hu[(size_t)(i + 1) * (C3 / 2) + t];
        unsigned int u2 = hu[(size_t)(i + 2) * (C3 / 2) + t];
        unsigned int u3 = hu[(size_t)(i + 3) * (C3 / 2) + t];
        s0 += bflo(u0) + bflo(u1) + bflo(u2) + bflo(u3);
        s1 += bfhi(u0) + bfhi(u1) + bfhi(u2) + bfhi(u3);
    }
    for (; i < b; ++i) {
        unsigned int u = hu[(size_t)i * (C3 / 2) + t];
        s0 += bflo(u);
        s1 += bfhi(u);
    }
    atomicAdd(&pooled[g * C3 + 2 * t], s0);
    atomicAdd(&pooled[g * C3 + 2 * t + 1], s1);
}

// ---------------- head: mean-divide + linear + log_softmax ----------------

__global__ void finalize_head(const float* __restrict__ pooled, const int* __restrict__ batch,
                              const float* __restrict__ Wc, const float* __restrict__ bc,
                              float* __restrict__ outp) {
    int g = blockIdx.x;
    int t = threadIdx.x; // 128 threads = C3
    __shared__ int seg[2];
    if (t < 2) {
        int target = g + t;
        int lo = 0, hi = N_NODES;
        while (lo < hi) { int mid = (lo + hi) >> 1; if (batch[mid] < target) lo = mid + 1; else hi = mid; }
        seg[t] = lo;
    }
    __syncthreads();
    float cnt = (float)(seg[1] - seg[0]);
    float pv = pooled[(size_t)g * C3 + t] / fmaxf(cnt, 1.f);
    float p0 = pv * Wc[t * 2 + 0];
    float p1 = pv * Wc[t * 2 + 1];
#pragma unroll
    for (int o = 32; o > 0; o >>= 1) {
        p0 += __shfl_down(p0, o);
        p1 += __shfl_down(p1, o);
    }
    __shared__ float r0[2], r1[2];
    int wid = t >> 6, lane = t & 63;
    if (lane == 0) { r0[wid] = p0; r1[wid] = p1; }
    __syncthreads();
    if (t == 0) {
        float l0 = r0[0] + r0[1] + bc[0];
        float l1 = r1[0] + r1[1] + bc[1];
        float mx = fmaxf(l0, l1);
        float lse = mx + logf(expf(l0 - mx) + expf(l1 - mx));
        outp[g * 2 + 0] = l0 - lse;
        outp[g * 2 + 1] = l1 - lse;
    }
}

// ---------------- launch ----------------

extern "C" void kernel_launch(void* const* d_in, const int* in_sizes, int n_in,
                              void* d_out, int out_size, void* d_ws, size_t ws_size,
                              hipStream_t stream) {
    const float* x = (const float*)d_in[0];
    const float* W1 = (const float*)d_in[1];
    const float* b1 = (const float*)d_in[2];
    const float* W2 = (const float*)d_in[3];
    const float* b2 = (const float*)d_in[4];
    const float* W3 = (const float*)d_in[5];
    const float* b3 = (const float*)d_in[6];
    const float* Wc = (const float*)d_in[7];
    const float* bc = (const float*)d_in[8];
    const int* ei = (const int*)d_in[9];
    const int* batch = (const int*)d_in[10];
    const int* row = ei;
    const int* col = ei + N_EDGES;
    float* out = (float*)d_out;

    char* ws = (char*)d_ws;
    size_t off = 0;
    auto alloc = [&](size_t bytes) -> void* {
        off = (off + 255) & ~(size_t)255;
        void* p = ws + off;
        off += bytes;
        return p;
    };

    int* counts = (int*)alloc((size_t)N_NODES * 4);
    int* offsets = (int*)alloc((size_t)(N_NODES + 1) * 4);
    int* cursor = (int*)alloc((size_t)N_NODES * 4);
    int* chunksums = (int*)alloc(256 * 4);
    float* dis = (float*)alloc((size_t)N_NODES * 4);
    int* csr_src = (int*)alloc((size_t)N_EDGES * 4);
    float* csr_w = (float*)alloc((size_t)N_EDGES * 4);
    float* aggx = (float*)alloc((size_t)N_NODES * 3 * 4);
    short* W2t = (short*)alloc((size_t)C1 * C2 * 2);   // [C2][C1] bf16
    short* W3t = (short*)alloc((size_t)C2 * C3 * 2);   // [C3][C2] bf16
    short* h1 = (short*)alloc((size_t)N_NODES * C1 * 2);
    short* m2 = (short*)alloc((size_t)N_NODES * C2 * 2);
    short* h2 = (short*)alloc((size_t)N_NODES * C2 * 2);
    short* m3 = (short*)alloc((size_t)N_NODES * C3 * 2);
    short* h3 = (short*)alloc((size_t)N_NODES * C3 * 2);
    float* pooled = (float*)alloc((size_t)NGRAPH * C3 * 4);

    hipMemsetAsync(counts, 0, (size_t)N_NODES * 4, stream);
    hipMemsetAsync(pooled, 0, (size_t)NGRAPH * C3 * 4, stream);
    count_edges<<<(N_EDGES + 255) / 256, 256, 0, stream>>>(col, counts);
    compute_dis<<<(N_NODES + 255) / 256, 256, 0, stream>>>(counts, dis);
    int nchunks = (N_NODES + 255) / 256;
    scan_chunks<<<nchunks, 256, 0, stream>>>(counts, offsets, chunksums);
    scan_sums<<<1, 256, 0, stream>>>(chunksums, nchunks);
    finalize_offsets<<<(N_NODES + 255) / 256, 256, 0, stream>>>(offsets, chunksums);
    init_cursor<<<(N_NODES + 255) / 256, 256, 0, stream>>>(offsets, cursor);
    scatter_edges<<<(N_EDGES + 255) / 256, 256, 0, stream>>>(row, col, dis, cursor, csr_src, csr_w);

    transp_bf16<<<(C1 * C2 + 255) / 256, 256, 0, stream>>>(W2, W2t, C1, C2);
    transp_bf16<<<(C2 * C3 + 255) / 256, 256, 0, stream>>>(W3, W3t, C2, C3);

    agg_feat3<<<(N_NODES + 255) / 256, 256, 0, stream>>>(x, offsets, csr_src, csr_w, dis, aggx);
    layer1<<<N_NODES, C1 / 2, 0, stream>>>(aggx, W1, b1, h1);

    dim3 g2((N_NODES + 127) / 128, C2 / 64);
    gemm_bf16<C1><<<g2, 256, 0, stream>>>(h1, W2t, m2, N_NODES, C2);
    aggregate_bf<C2><<<N_NODES, C2 / 2, 0, stream>>>(m2, offsets, csr_src, csr_w, dis, b2, h2);

    dim3 g3((N_NODES + 127) / 128, C3 / 64);
    gemm_bf16<C2><<<g3, 256, 0, stream>>>(h2, W3t, m3, N_NODES, C3);
    aggregate_bf<C3><<<N_NODES, C3 / 2, 0, stream>>>(m3, offsets, csr_src, csr_w, dis, b3, h3);

    dim3 gp(NGRAPH, PSPLIT);
    pool_partial<<<gp, C3 / 2, 0, stream>>>(h3, batch, pooled);
    finalize_head<<<NGRAPH, C3, 0, stream>>>(pooled, batch, Wc, bc, out);
}